// Round 7
// baseline (85.776 us; speedup 1.0000x reference)
//
#include <hip/hip_runtime.h>
#include <hip/hip_cooperative_groups.h>

namespace cg = cooperative_groups;

#define NUM_LABELS 20
#define N_PIX 4096
#define C_DIM 16
#define BATCH 4

#define PTILE 128
#define PNT (N_PIX / PTILE)               // 32
#define PTPAIRS (PNT * (PNT + 1) / 2)     // 528
#define NPAIRS (BATCH * PTPAIRS)          // 2112
#define NBLK 704                          // 704 * 3 = 2112
#define PAIRS_PER_BLK 3
#define KPAD 24                           // LDS row stride in shorts (48 B)

typedef __attribute__((ext_vector_type(8))) short bf16x8;
typedef __attribute__((ext_vector_type(4))) float f32x4;

__device__ __forceinline__ unsigned int bf16rne(float f) {
    unsigned int x = __float_as_uint(f);
    return (x + 0x7fffu + ((x >> 16) & 1u)) >> 16;
}

// Single fused kernel:
//   out = [ 0.5*sum_b P_b - 0.5*sum_i |g_i|^2 + sum_b sum_{i<j} (eq ? -s : max(s,0)) ] / N
// with g = (1/cnt[y]) * normalize(center(x)), s = bf16(g_i).bf16(g_j) via MFMA.
__global__ __launch_bounds__(256, 3) void fused_kernel(
    const float* __restrict__ emb,        // [B][C][N]
    const int*   __restrict__ lab,        // [B][N]
    float* __restrict__ partials,         // [NBLK]
    float* __restrict__ out)              // [1]
{
    const int bk   = blockIdx.x;
    const int t    = threadIdx.x;
    const int lane = t & 63;
    const int wv   = t >> 6;

    __shared__ int   hist[BATCH][NUM_LABELS];
    __shared__ float rinv[BATCH][NUM_LABELS];
    __shared__ unsigned short sI[PTILE * KPAD];
    __shared__ unsigned short sJ[PTILE * KPAD];
    __shared__ int   syI[PTILE], syJ[PTILE];
    __shared__ float wred[4];
    __shared__ double sd[256];

    // ---- per-block label histograms (labels are L2-resident, 64 KB total) --
    for (int i = t; i < BATCH * NUM_LABELS; i += 256) (&hist[0][0])[i] = 0;
    __syncthreads();
#pragma unroll
    for (int b = 0; b < BATCH; ++b)
        for (int n = t; n < N_PIX; n += 256)
            atomicAdd(&hist[b][lab[b * N_PIX + n]], 1);
    __syncthreads();
    if (t < BATCH * NUM_LABELS) {
        const int c = (&hist[0][0])[t];
        (&rinv[0][0])[t] = (c > 0) ? 1.0f / (float)c : 0.0f;
    }
    __syncthreads();

    float sum = 0.f;
    if (bk == 0 && t == 0) {             // + 0.5 * sum_b (#present labels)
        int p = 0;
#pragma unroll
        for (int i = 0; i < BATCH * NUM_LABELS; ++i) p += ((&hist[0][0])[i] > 0) ? 1 : 0;
        sum += 0.5f * (float)p;
    }

    // ---- 3 tile-pairs per block -------------------------------------------
    for (int pi = 0; pi < PAIRS_PER_BLK; ++pi) {
        const int p  = bk + pi * NBLK;
        const int b  = p / PTPAIRS;
        const int k0 = p % PTPAIRS;

        // decode upper-triangle tile pair (ti <= tj)
        const float nn = (float)PNT;
        int ti = (int)(((2.f * nn + 1.f) -
                        sqrtf((2.f * nn + 1.f) * (2.f * nn + 1.f) - 8.f * (float)k0)) * 0.5f);
        if (ti < 0) ti = 0;
        if (ti > PNT - 1) ti = PNT - 1;
        auto rowoff = [](int r) { return r * PNT - (r * (r - 1)) / 2; };
        while (ti > 0 && k0 < rowoff(ti)) --ti;
        while (ti < PNT - 1 && k0 >= rowoff(ti + 1)) ++ti;
        const int tj = ti + (k0 - rowoff(ti));
        const bool diag = (ti == tj);

        __syncthreads();   // previous iteration's LDS reads done

        // ---- normalize own tiles straight from emb into LDS bf16 ----------
        {
            const int side = t >> 7;          // 0 -> tile I, 1 -> tile J
            const int row  = t & 127;
            const int tile = side ? tj : ti;
            const int gidx = b * N_PIX + tile * PTILE + row;
            const float* xb = emb + (size_t)b * C_DIM * N_PIX + tile * PTILE + row;

            float v[C_DIM];
            float s = 0.f;
#pragma unroll
            for (int c = 0; c < C_DIM; ++c) { v[c] = xb[(size_t)c * N_PIX]; s += v[c]; }
            const float mean = s * (1.0f / C_DIM);
            float ss = 0.f;
#pragma unroll
            for (int c = 0; c < C_DIM; ++c) { v[c] -= mean; ss += v[c] * v[c]; }
            const float nrm = sqrtf(ss);
            const int   y   = lab[gidx];
            const float w   = rinv[b][y];
            const float inv = (nrm > 0.f) ? (w / nrm) : 0.f;

            unsigned int u[8];
#pragma unroll
            for (int k = 0; k < 8; ++k) {
                const unsigned int lo = bf16rne(v[2 * k] * inv);
                const unsigned int hi = bf16rne(v[2 * k + 1] * inv);
                u[k] = lo | (hi << 16);
            }
            unsigned short* dst = side ? sJ : sI;
            *reinterpret_cast<uint4*>(&dst[row * KPAD])     = make_uint4(u[0], u[1], u[2], u[3]);
            *reinterpret_cast<uint4*>(&dst[row * KPAD + 8]) = make_uint4(u[4], u[5], u[6], u[7]);
            (side ? syJ : syI)[row] = y;

            // diagonal blocks own the -0.5*|g_f32|^2 term for their tile
            if (diag && side == 0) sum -= 0.5f * (inv * inv * ss);
        }
        __syncthreads();

        // ---- MFMA + epilogue ----------------------------------------------
        const int lo16 = lane & 15;
        const int hi   = lane >> 4;            // 0..3
        const bool doread = (hi < 2);          // K=16 real; hi>=2 lanes zero

        bf16x8 afrag[2] = {bf16x8{}, bf16x8{}};
        int    yIr[2][4];
#pragma unroll
        for (int rt = 0; rt < 2; ++rt) {
            const int rtile = wv * 2 + rt;
            if (doread)
                afrag[rt] = *reinterpret_cast<const bf16x8*>(&sI[(rtile * 16 + lo16) * KPAD + hi * 8]);
            const int4 yv = *reinterpret_cast<const int4*>(&syI[rtile * 16 + hi * 4]);
            yIr[rt][0] = yv.x; yIr[rt][1] = yv.y; yIr[rt][2] = yv.z; yIr[rt][3] = yv.w;
        }

#pragma unroll
        for (int ct = 0; ct < 8; ++ct) {
            bf16x8 bfrag = bf16x8{};
            if (doread)
                bfrag = *reinterpret_cast<const bf16x8*>(&sJ[(ct * 16 + lo16) * KPAD + hi * 8]);
            const int yq = syJ[ct * 16 + lo16];
#pragma unroll
            for (int rt = 0; rt < 2; ++rt) {
                const int rtile = wv * 2 + rt;
                if (diag && rtile > ct) continue;      // below diagonal: skip
                f32x4 acc = {0.f, 0.f, 0.f, 0.f};
                acc = __builtin_amdgcn_mfma_f32_16x16x32_bf16(afrag[rt], bfrag, acc, 0, 0, 0);
                if (diag && rtile == ct) {
#pragma unroll
                    for (int j = 0; j < 4; ++j) {
                        const float s = acc[j];
                        const float v = (yIr[rt][j] == yq) ? -s : fmaxf(s, 0.f);
                        const int iloc = hi * 4 + j;
                        sum += (iloc < lo16) ? v : 0.f;   // strict i<j
                    }
                } else {
#pragma unroll
                    for (int j = 0; j < 4; ++j) {
                        const float s = acc[j];
                        sum += (yIr[rt][j] == yq) ? -s : fmaxf(s, 0.f);
                    }
                }
            }
        }
    }

    // ---- block reduction ---------------------------------------------------
#pragma unroll
    for (int off = 32; off > 0; off >>= 1) sum += __shfl_down(sum, off);
    if (lane == 0) wred[wv] = sum;
    __syncthreads();
    if (t == 0) partials[bk] = wred[0] + wred[1] + wred[2] + wred[3];

    // ---- grid-wide barrier, block 0 reduces deterministically --------------
    cg::this_grid().sync();

    if (bk == 0) {
        double s = 0.0;
        for (int i = t; i < NBLK; i += 256) s += (double)partials[i];
        sd[t] = s;
        __syncthreads();
#pragma unroll
        for (int k = 128; k > 0; k >>= 1) {
            if (t < k) sd[t] += sd[t + k];
            __syncthreads();
        }
        if (t == 0) out[0] = (float)(sd[0] * (1.0 / (double)N_PIX));
    }
}

extern "C" void kernel_launch(void* const* d_in, const int* in_sizes, int n_in,
                              void* d_out, int out_size, void* d_ws, size_t ws_size,
                              hipStream_t stream) {
    const float* emb = (const float*)d_in[0];
    const int*   lab = (const int*)d_in[1];
    float* out = (float*)d_out;
    float* partials = (float*)d_ws;        // NBLK floats

    void* args[] = {(void*)&emb, (void*)&lab, (void*)&partials, (void*)&out};
    hipLaunchCooperativeKernel((const void*)fused_kernel,
                               dim3(NBLK), dim3(256), args, 0, stream);
}